// Round 2
// baseline (56.582 us; speedup 1.0000x reference)
//
#include <hip/hip_runtime.h>
#include <math.h>

// ---------------- workspace layout (floats) ----------------
#define WS_HXPART 0          // [8 chunk][8 n][256 j] partial x_feat @ g1_lin[:510]
#define WS_XCNN   16384      // [8][2] CNN_1 output
#define WS_HE1    16400      // [24][256] ea1 @ g1_le
#define WS_EANEW  22544      // [16][64]
#define WS_HE2    23568      // [24][64]
#define WS_WF     25104      // [128][10] fused c2l1w@c2l2w
#define WS_BF     26384      // [10]      fused bias
#define WS_VM     26394      // [3][64] means: x2 / ea_new even / ea_new odd
#define WS_PP     26586      // [3 tau][4 chunk][640] deconv partials
// total 34266 floats = 137 KB

// ================= K1: parallel precompute =================
__global__ __launch_bounds__(256) void k1_pre(
    const float* __restrict__ xf,   const float* __restrict__ xft,
    const float* __restrict__ ea,
    const float* __restrict__ c1w1, const float* __restrict__ c1b1,
    const float* __restrict__ c1w2, const float* __restrict__ c1b2,
    const float* __restrict__ g1lin,const float* __restrict__ g1le,
    const float* __restrict__ mw1,  const float* __restrict__ mb1,
    const float* __restrict__ mw2,  const float* __restrict__ mb2,
    const float* __restrict__ g2le,
    const float* __restrict__ l1w,  const float* __restrict__ l1b,
    const float* __restrict__ l2w,  const float* __restrict__ l2b,
    float* __restrict__ ws)
{
    const int b = blockIdx.x, tid = threadIdx.x;
    if (b < 8) {
        // hx partial chunk b: k in [b*64, b*64+klen), 510 = 7*64+62
        __shared__ float sx[8][64];
        const int k0 = b * 64;
        const int klen = (b == 7) ? 62 : 64;
        for (int idx = tid; idx < 512; idx += 256) {
            int n = idx >> 6, kk = idx & 63;
            sx[n][kk] = (kk < klen) ? xf[n * 510 + k0 + kk] : 0.f;
        }
        __syncthreads();
        const int j = tid;
        float acc[8];
        #pragma unroll
        for (int n = 0; n < 8; ++n) acc[n] = 0.f;
        for (int kk = 0; kk < 64; ++kk) {
            float w = g1lin[(k0 + kk) * 256 + j];   // rows 510/511 hit *0 -> harmless
            #pragma unroll
            for (int n = 0; n < 8; ++n) acc[n] += sx[n][kk] * w;
        }
        #pragma unroll
        for (int n = 0; n < 8; ++n) ws[WS_HXPART + (b * 8 + n) * 256 + j] = acc[n];
    } else if (b < 12) {
        // he1 = [edge_attr ; mean] @ g1_le, column chunk (64 cols)
        __shared__ float sea[17 * 128];
        for (int idx = tid; idx < 2048; idx += 256) sea[idx] = ea[idx];
        __syncthreads();
        if (tid < 128) {
            float m = 0.f;
            for (int e = 0; e < 16; ++e) m += sea[e * 128 + tid];
            sea[16 * 128 + tid] = m * (1.f / 16.f);
        }
        __syncthreads();
        const int cc = b - 8;
        for (int o = tid; o < 1536; o += 256) {
            int e = o >> 6, j = cc * 64 + (o & 63);
            int row = (e < 16) ? e : 16;
            float acc = 0.f;
            for (int k = 0; k < 128; ++k) acc += sea[row * 128 + k] * g1le[k * 256 + j];
            ws[WS_HE1 + e * 256 + j] = acc;
        }
    } else if (b == 12) {
        // CNN_1
        __shared__ float t2[160], y1[160], y2[16];
        if (tid < 160) {
            int b_ = tid / 80, ch = (tid % 80) / 10, tt = tid % 10;
            int srow = ((ch & 1) == 0) ? 1 : 5;
            int n = 4 * b_ + (ch >> 1);
            t2[tid] = xft[srow * 80 + n * 10 + tt];
        }
        __syncthreads();
        if (tid < 160) {
            int b_ = tid / 80, co = (tid % 80) / 10, tt = tid % 10;
            float acc = c1b1[co];
            for (int ci = 0; ci < 8; ++ci)
                for (int k = 0; k < 3; ++k) {
                    int p = tt + k - 1;
                    if (p >= 0 && p < 10) acc += t2[b_ * 80 + ci * 10 + p] * c1w1[co * 24 + ci * 3 + k];
                }
            y1[tid] = fmaxf(acc, 0.f);
        }
        __syncthreads();
        if (tid < 16) {
            int b_ = tid >> 3, p = tid & 7;
            float acc = c1b2[0];
            for (int i = 0; i < 10; ++i)
                for (int k = 0; k < 3; ++k) {
                    int q = p + k - 1;
                    if (q >= 0 && q < 8) acc += y1[b_ * 80 + q * 10 + i] * c1w2[i * 3 + k];
                }
            y2[tid] = acc;
        }
        __syncthreads();
        if (tid < 16) ws[WS_XCNN + tid] = fmaxf(y2[tid], 0.f);  // flat [2,1,8] == flat [8,2]
    } else if (b == 13) {
        // edge MLP -> ea_new ; mean ; he2 = [ea_new ; mean] @ g2_le
        __shared__ float sea[2048];
        __shared__ float tmp[1024];
        __shared__ float ean[17 * 64];
        for (int idx = tid; idx < 2048; idx += 256) sea[idx] = ea[idx];
        __syncthreads();
        for (int o = tid; o < 1024; o += 256) {
            int e = o >> 6, c = o & 63;
            float acc = mb1[c];
            for (int k = 0; k < 128; ++k) acc += sea[e * 128 + k] * mw1[k * 64 + c];
            tmp[o] = fmaxf(acc, 0.f);
        }
        __syncthreads();
        for (int o = tid; o < 1024; o += 256) {
            int e = o >> 6, c = o & 63;
            float acc = mb2[c];
            for (int k = 0; k < 64; ++k) acc += tmp[e * 64 + k] * mw2[k * 64 + c];
            ean[o] = acc;
            ws[WS_EANEW + o] = acc;
        }
        __syncthreads();
        if (tid < 64) {
            float m = 0.f;
            for (int e = 0; e < 16; ++e) m += ean[e * 64 + tid];
            ean[1024 + tid] = m * (1.f / 16.f);
        }
        __syncthreads();
        for (int o = tid; o < 1536; o += 256) {
            int e = o >> 6, c = o & 63;
            int row = (e < 16) ? e : 16;
            float acc = 0.f;
            for (int k = 0; k < 64; ++k) acc += ean[row * 64 + k] * g2le[k * 64 + c];
            ws[WS_HE2 + o] = acc;
        }
    } else {
        // fused tail linear: wf = c2l1w @ c2l2w ; bf = c2l1b @ c2l2w + c2l2b
        __shared__ float sl2[2560];
        for (int idx = tid; idx < 2560; idx += 256) sl2[idx] = l2w[idx];
        __syncthreads();
        const int wc = b - 14;      // 0..7, 16 m-rows each
        const int m0 = wc * 16;
        if (tid < 160) {
            int ml = tid / 10, t = tid % 10;
            int m = m0 + ml;
            float acc = 0.f;
            for (int j = 0; j < 256; ++j) acc += l1w[m * 256 + j] * sl2[j * 10 + t];
            ws[WS_WF + m * 10 + t] = acc;
        } else if (wc == 0 && tid < 170) {
            int t = tid - 160;
            float acc = l2b[t];
            for (int j = 0; j < 256; ++j) acc += l1b[j] * sl2[j * 10 + t];
            ws[WS_BF + t] = acc;
        }
    }
}

// ================= K2: GAT1 -> GAT2 -> means (single block) =================
__global__ __launch_bounds__(512) void k2_gat(
    const float* __restrict__ g1lin,
    const float* __restrict__ g1as, const float* __restrict__ g1ad,
    const float* __restrict__ g1ae, const float* __restrict__ g1b,
    const float* __restrict__ g2lin,
    const float* __restrict__ g2as, const float* __restrict__ g2ad,
    const float* __restrict__ g2ae, const float* __restrict__ g2b,
    const int* __restrict__ eidx,
    float* __restrict__ ws)
{
    const int tid = threadIdx.x;
    __shared__ float h[8 * 256];
    __shared__ float x1[8 * 256];
    __shared__ float h2[8 * 64];
    __shared__ float x2[8 * 64];
    __shared__ float ss1[32], sd1[32], se1[96], al1[96], wt1[96], mx1[32], dn1[32];
    __shared__ float ss2[8], sd2[8], se2[24], al2[24], wt2[24], mx2[8], dn2[8];
    __shared__ int   esrc[24], edst[24];
    __shared__ float sxc[16];

    if (tid < 16) sxc[tid] = ws[WS_XCNN + tid];
    if (tid < 24) {
        esrc[tid] = (tid < 16) ? eidx[tid]      : (tid - 16);
        edst[tid] = (tid < 16) ? eidx[16 + tid] : (tid - 16);
    }
    __syncthreads();

    // h[n][j] = sum of 8 partials + x_cnn rows (g1_lin rows 510,511)
    {
        const int j = tid & 255, half = tid >> 8;
        for (int nl = 0; nl < 4; ++nl) {
            int n = half * 4 + nl;
            float acc = 0.f;
            #pragma unroll
            for (int cb = 0; cb < 8; ++cb) acc += ws[WS_HXPART + (cb * 8 + n) * 256 + j];
            acc += sxc[n * 2 + 0] * g1lin[510 * 256 + j] + sxc[n * 2 + 1] * g1lin[511 * 256 + j];
            h[n * 256 + j] = acc;
        }
    }
    __syncthreads();
    if (tid < 32) {                       // src/dst scores (4 heads)
        int n = tid >> 2, hd = tid & 3;
        float aS = 0.f, aD = 0.f;
        for (int c = 0; c < 64; ++c) {
            float hv = h[n * 256 + hd * 64 + c];
            aS += hv * g1as[hd * 64 + c];
            aD += hv * g1ad[hd * 64 + c];
        }
        ss1[tid] = aS; sd1[tid] = aD;
    } else if (tid < 128) {               // edge scores
        int idx = tid - 32;
        int e = idx >> 2, hd = idx & 3;
        float acc = 0.f;
        for (int c = 0; c < 64; ++c) acc += ws[WS_HE1 + e * 256 + hd * 64 + c] * g1ae[hd * 64 + c];
        se1[idx] = acc;
    }
    __syncthreads();
    if (tid < 96) {
        int e = tid >> 2, hd = tid & 3;
        float s = ss1[esrc[e] * 4 + hd] + sd1[edst[e] * 4 + hd] + se1[tid];
        al1[tid] = (s > 0.f) ? s : 0.2f * s;
    }
    __syncthreads();
    if (tid < 32) {                       // scatter-softmax stats per (dst, head)
        int n = tid >> 2, hd = tid & 3;
        float mx = -1e30f;
        for (int e = 0; e < 24; ++e) if (edst[e] == n) mx = fmaxf(mx, al1[e * 4 + hd]);
        float dn = 0.f;
        for (int e = 0; e < 24; ++e) if (edst[e] == n) dn += expf(al1[e * 4 + hd] - mx);
        mx1[tid] = mx; dn1[tid] = dn;
    }
    __syncthreads();
    if (tid < 96) {
        int e = tid >> 2, hd = tid & 3, d = edst[e];
        wt1[tid] = expf(al1[tid] - mx1[d * 4 + hd]) / (dn1[d * 4 + hd] + 1e-16f);
    }
    __syncthreads();
    {   // aggregate + bias + relu -> x1
        const int j = tid & 255, half = tid >> 8, hd = j >> 6;
        for (int nl = 0; nl < 4; ++nl) {
            int n = half * 4 + nl;
            float acc = 0.f;
            for (int e = 0; e < 24; ++e)
                if (edst[e] == n) acc += wt1[e * 4 + hd] * h[esrc[e] * 256 + j];
            x1[n * 256 + j] = fmaxf(acc + g1b[j], 0.f);
        }
    }
    __syncthreads();
    {   // GAT2: h2 = x1 @ g2_lin
        int n = tid >> 6, c = tid & 63;
        float acc = 0.f;
        for (int k = 0; k < 256; ++k) acc += x1[n * 256 + k] * g2lin[k * 64 + c];
        h2[tid] = acc;
    }
    __syncthreads();
    if (tid < 8) {
        float aS = 0.f, aD = 0.f;
        for (int c = 0; c < 64; ++c) {
            float hv = h2[tid * 64 + c];
            aS += hv * g2as[c]; aD += hv * g2ad[c];
        }
        ss2[tid] = aS; sd2[tid] = aD;
    } else if (tid < 32) {
        int e = tid - 8;
        float acc = 0.f;
        for (int c = 0; c < 64; ++c) acc += ws[WS_HE2 + e * 64 + c] * g2ae[c];
        se2[e] = acc;
    }
    __syncthreads();
    if (tid < 24) {
        float s = ss2[esrc[tid]] + sd2[edst[tid]] + se2[tid];
        al2[tid] = (s > 0.f) ? s : 0.2f * s;
    }
    __syncthreads();
    if (tid < 8) {
        float mx = -1e30f;
        for (int e = 0; e < 24; ++e) if (edst[e] == tid) mx = fmaxf(mx, al2[e]);
        float dn = 0.f;
        for (int e = 0; e < 24; ++e) if (edst[e] == tid) dn += expf(al2[e] - mx);
        mx2[tid] = mx; dn2[tid] = dn;
    }
    __syncthreads();
    if (tid < 24) {
        int d = edst[tid];
        wt2[tid] = expf(al2[tid] - mx2[d]) / (dn2[d] + 1e-16f);
    }
    __syncthreads();
    {
        int n = tid >> 6, c = tid & 63;
        float acc = 0.f;
        for (int e = 0; e < 24; ++e)
            if (edst[e] == n) acc += wt2[e] * h2[esrc[e] * 64 + c];
        x2[tid] = fmaxf(acc + g2b[c], 0.f);
    }
    __syncthreads();
    // means feeding the deconv einsums: mean(x2), mean(ea_new[::2]), mean(ea_new[1::2])
    if (tid < 64) {
        float m = 0.f;
        for (int n = 0; n < 8; ++n) m += x2[n * 64 + tid];
        ws[WS_VM + tid] = m * 0.125f;
    } else if (tid < 128) {
        int c = tid - 64;
        float m = 0.f;
        for (int e = 0; e < 16; e += 2) m += ws[WS_EANEW + e * 64 + c];
        ws[WS_VM + 64 + c] = m * 0.125f;
    } else if (tid < 192) {
        int c = tid - 128;
        float m = 0.f;
        for (int e = 1; e < 16; e += 2) m += ws[WS_EANEW + e * 64 + c];
        ws[WS_VM + 128 + c] = m * 0.125f;
    }
}

// ================= K3: deconv einsums (mean-vector @ [64,64,10]) =================
__global__ __launch_bounds__(640) void k3_deconv(
    const float* __restrict__ d1w, const float* __restrict__ d2w,
    const float* __restrict__ d3w, float* __restrict__ ws)
{
    __shared__ float sv[16];
    const int tau = blockIdx.x >> 2, cb = blockIdx.x & 3;
    const float* dw = (tau == 0) ? d1w : (tau == 1) ? d2w : d3w;
    if (threadIdx.x < 16) sv[threadIdx.x] = ws[WS_VM + tau * 64 + cb * 16 + threadIdx.x];
    __syncthreads();
    const int j = threadIdx.x;          // j = o*10 + t, coalesced over dw
    float acc = 0.f;
    #pragma unroll
    for (int ii = 0; ii < 16; ++ii) acc += sv[ii] * dw[(cb * 16 + ii) * 640 + j];
    ws[WS_PP + (tau * 4 + cb) * 640 + j] = acc;
}

// ================= K4: CNN_2 + fused linear -> output =================
__global__ __launch_bounds__(256) void k4_cnn2(
    const float* __restrict__ xft,
    const float* __restrict__ d1b, const float* __restrict__ d2b, const float* __restrict__ d3b,
    const float* __restrict__ c2w1, const float* __restrict__ c2b1,
    const float* __restrict__ c2w2, const float* __restrict__ c2b2,
    const float* __restrict__ ws, float* __restrict__ out)
{
    const int tid = threadIdx.x;
    const int r0 = blockIdx.x * 4;       // 4 rows of the 64-row batch per block
    __shared__ float sw2[6144];          // c2w2 [64][32][3]
    __shared__ float sw1[384];           // c2w1 [32][4][3]
    __shared__ float swf[1280];          // fused [128][10]
    __shared__ float sbf[10];
    __shared__ float cin[160];           // [4][4ch][10]
    __shared__ float u[1024];            // [4][32][8]
    __shared__ float v[512];             // [4][32][4]
    __shared__ float f[512];             // [4][128]
    for (int idx = tid; idx < 6144; idx += 256) sw2[idx] = c2w2[idx];
    for (int idx = tid; idx < 1280; idx += 256) swf[idx] = ws[WS_WF + idx];
    for (int idx = tid; idx < 384; idx += 256) sw1[idx] = c2w1[idx];   // FIXED: was if(tid<384) under 256 threads
    if (tid < 10) sbf[tid] = ws[WS_BF + tid];
    if (tid < 160) {
        int rl = tid / 40, ch = (tid % 40) / 10, t = tid % 10;
        int r = r0 + rl;
        float val;
        if (ch == 1) val = xft[r * 10 + t];                 // "inf" channel
        else {
            int tau = (ch == 0) ? 0 : (ch == 2) ? 1 : 2;
            float acc = 0.f;
            #pragma unroll
            for (int cb = 0; cb < 4; ++cb) acc += ws[WS_PP + (tau * 4 + cb) * 640 + r * 10 + t];
            const float* db = (tau == 0) ? d1b : (tau == 1) ? d2b : d3b;
            val = acc + db[r];
        }
        cin[rl * 40 + ch * 10 + t] = val;
    }
    __syncthreads();
    for (int o = tid; o < 1024; o += 256) {  // conv1, no relu, pad 0
        int rl = o >> 8, co = (o >> 3) & 31, p = o & 7;
        float acc = c2b1[co];
        #pragma unroll
        for (int ci = 0; ci < 4; ++ci)
            #pragma unroll
            for (int k = 0; k < 3; ++k)
                acc += cin[rl * 40 + ci * 10 + p + k] * sw1[co * 12 + ci * 3 + k];
        u[o] = acc;
    }
    __syncthreads();
    for (int o = tid; o < 512; o += 256) {   // maxpool(2)
        int rl = o >> 7, co = (o >> 2) & 31, q = o & 3;
        v[o] = fmaxf(u[rl * 256 + co * 8 + 2 * q], u[rl * 256 + co * 8 + 2 * q + 1]);
    }
    __syncthreads();
    for (int o = tid; o < 512; o += 256) {   // conv2 + flatten
        int rl = o >> 7, m = o & 127, co2 = m >> 1, p = m & 1;
        float acc = c2b2[co2];
        for (int ci = 0; ci < 32; ++ci)
            #pragma unroll
            for (int k = 0; k < 3; ++k)
                acc += v[rl * 128 + ci * 4 + p + k] * sw2[co2 * 96 + ci * 3 + k];
        f[rl * 128 + m] = acc;
    }
    __syncthreads();
    if (tid < 40) {                          // fused (l1 -> l2) + relu
        int rl = tid / 10, t = tid % 10;
        float acc = sbf[t];
        for (int m = 0; m < 128; ++m) acc += f[rl * 128 + m] * swf[m * 10 + t];
        out[(r0 + rl) * 10 + t] = fmaxf(acc, 0.f);
    }
}

extern "C" void kernel_launch(void* const* d_in, const int* in_sizes, int n_in,
                              void* d_out, int out_size, void* d_ws, size_t ws_size,
                              hipStream_t stream)
{
    const float* xf    = (const float*)d_in[0];
    const float* xft   = (const float*)d_in[1];
    const float* ea    = (const float*)d_in[2];
    const float* c1w1  = (const float*)d_in[3];
    const float* c1b1  = (const float*)d_in[4];
    const float* c1w2  = (const float*)d_in[5];
    const float* c1b2  = (const float*)d_in[6];
    const float* g1lin = (const float*)d_in[7];
    const float* g1as  = (const float*)d_in[8];
    const float* g1ad  = (const float*)d_in[9];
    const float* g1le  = (const float*)d_in[10];
    const float* g1ae  = (const float*)d_in[11];
    const float* g1b   = (const float*)d_in[12];
    const float* g2lin = (const float*)d_in[13];
    const float* g2as  = (const float*)d_in[14];
    const float* g2ad  = (const float*)d_in[15];
    const float* g2le  = (const float*)d_in[16];
    const float* g2ae  = (const float*)d_in[17];
    const float* g2b   = (const float*)d_in[18];
    const float* mw1   = (const float*)d_in[19];
    const float* mb1   = (const float*)d_in[20];
    const float* mw2   = (const float*)d_in[21];
    const float* mb2   = (const float*)d_in[22];
    const float* d1w   = (const float*)d_in[23];
    const float* d1b   = (const float*)d_in[24];
    const float* d2w   = (const float*)d_in[25];
    const float* d2b   = (const float*)d_in[26];
    const float* d3w   = (const float*)d_in[27];
    const float* d3b   = (const float*)d_in[28];
    const float* c2w1  = (const float*)d_in[29];
    const float* c2b1  = (const float*)d_in[30];
    const float* c2w2  = (const float*)d_in[31];
    const float* c2b2  = (const float*)d_in[32];
    const float* l1w   = (const float*)d_in[33];
    const float* l1b   = (const float*)d_in[34];
    const float* l2w   = (const float*)d_in[35];
    const float* l2b   = (const float*)d_in[36];
    const int*   eidx  = (const int*)d_in[37];
    float* ws  = (float*)d_ws;
    float* out = (float*)d_out;

    hipLaunchKernelGGL(k1_pre, dim3(22), dim3(256), 0, stream,
        xf, xft, ea, c1w1, c1b1, c1w2, c1b2, g1lin, g1le,
        mw1, mb1, mw2, mb2, g2le, l1w, l1b, l2w, l2b, ws);
    hipLaunchKernelGGL(k2_gat, dim3(1), dim3(512), 0, stream,
        g1lin, g1as, g1ad, g1ae, g1b, g2lin, g2as, g2ad, g2ae, g2b, eidx, ws);
    hipLaunchKernelGGL(k3_deconv, dim3(12), dim3(640), 0, stream, d1w, d2w, d3w, ws);
    hipLaunchKernelGGL(k4_cnn2, dim3(16), dim3(256), 0, stream,
        xft, d1b, d2b, d3b, c2w1, c2b1, c2w2, c2b2, ws, out);
}